// Round 1
// baseline (4166.330 us; speedup 1.0000x reference)
//
#include <hip/hip_runtime.h>
#include <hip/hip_bf16.h>
#include <cstdint>

#define DIM 64
#define NT 4
#define TD 256   // NT*DIM
#define NSTEPS 5

__device__ __forceinline__ float sigmoidf(float x) { return 1.0f / (1.0f + expf(-x)); }

// h_all[n, t, e] = sum_d h[n,d] * W[t,e,d] + b[t,e]
// thread tid owns (t,e) = (tid>>6, tid&63); W row cached in 64 VGPRs.
__global__ __launch_bounds__(256, 2) void k_transform(
    const float* __restrict__ h, const float* __restrict__ W,
    const float* __restrict__ b, float* __restrict__ h_all, int n_nodes) {
  const int tid = threadIdx.x;
  float wreg[DIM];
#pragma unroll
  for (int d4 = 0; d4 < DIM / 4; ++d4) {
    float4 v = *(const float4*)(W + (size_t)tid * DIM + d4 * 4);
    wreg[d4 * 4 + 0] = v.x; wreg[d4 * 4 + 1] = v.y;
    wreg[d4 * 4 + 2] = v.z; wreg[d4 * 4 + 3] = v.w;
  }
  const float bias = b[tid];
  __shared__ float hs[4][DIM];

  for (int base = blockIdx.x * 4; base < n_nodes; base += gridDim.x * 4) {
    __syncthreads();  // protect previous iteration's hs reads
    {
      int idx = base * DIM + tid;              // 4 rows * 64 = 256 floats
      ((float*)hs)[tid] = (idx < n_nodes * DIM) ? h[idx] : 0.0f;
    }
    __syncthreads();
#pragma unroll
    for (int j = 0; j < 4; ++j) {
      if (base + j >= n_nodes) break;
      float acc = bias;
#pragma unroll
      for (int d = 0; d < DIM; ++d) acc = fmaf(hs[j][d], wreg[d], acc);
      h_all[(size_t)(base + j) * TD + tid] = acc;
    }
  }
}

// per edge: a[dst] += h_all[src, etype]; 16 lanes per edge, float4 each.
__global__ __launch_bounds__(256) void k_edge(
    const float* __restrict__ h_all, const int* __restrict__ src,
    const int* __restrict__ dst, const int* __restrict__ et,
    float* __restrict__ abuf, int n_edges) {
  int gid = blockIdx.x * 256 + threadIdx.x;
  int e = gid >> 4;
  if (e >= n_edges) return;
  int q = gid & 15;
  int s = src[e];
  int d0 = dst[e];
  int t = et[e];
  const float4 v = *(const float4*)(h_all + (size_t)s * TD + t * DIM + q * 4);
  float* ap = abuf + (size_t)d0 * DIM + q * 4;
  atomicAdd(ap + 0, v.x);
  atomicAdd(ap + 1, v.y);
  atomicAdd(ap + 2, v.z);
  atomicAdd(ap + 3, v.w);
}

// GRU: threads 0..191 own gate row g (w_ih[g,:], w_hh[g,:] in 128 VGPRs),
// then all 256 threads finalize 4 nodes x 64 dims.
__global__ __launch_bounds__(256, 2) void k_gru(
    const float* __restrict__ a, float* __restrict__ h,
    const float* __restrict__ w_ih, const float* __restrict__ w_hh,
    const float* __restrict__ b_ih, const float* __restrict__ b_hh,
    int n_nodes) {
  const int tid = threadIdx.x;
  float wi[DIM], wh[DIM];
  float bi = 0.0f, bh = 0.0f;
  if (tid < 3 * DIM) {
#pragma unroll
    for (int d4 = 0; d4 < DIM / 4; ++d4) {
      float4 v = *(const float4*)(w_ih + (size_t)tid * DIM + d4 * 4);
      wi[d4 * 4 + 0] = v.x; wi[d4 * 4 + 1] = v.y;
      wi[d4 * 4 + 2] = v.z; wi[d4 * 4 + 3] = v.w;
      float4 u = *(const float4*)(w_hh + (size_t)tid * DIM + d4 * 4);
      wh[d4 * 4 + 0] = u.x; wh[d4 * 4 + 1] = u.y;
      wh[d4 * 4 + 2] = u.z; wh[d4 * 4 + 3] = u.w;
    }
    bi = b_ih[tid];
    bh = b_hh[tid];
  }

  __shared__ float as_[4][DIM];
  __shared__ float hs_[4][DIM];
  __shared__ float rz[4][2 * DIM];
  __shared__ float nn[4][2][DIM];

  for (int base = blockIdx.x * 4; base < n_nodes; base += gridDim.x * 4) {
    __syncthreads();  // protect previous iteration
    {
      int idx = base * DIM + tid;
      bool ok = idx < n_nodes * DIM;
      ((float*)as_)[tid] = ok ? a[idx] : 0.0f;
      ((float*)hs_)[tid] = ok ? h[idx] : 0.0f;
    }
    __syncthreads();
    if (tid < 3 * DIM) {
#pragma unroll
      for (int j = 0; j < 4; ++j) {
        float gi = bi, gh = bh;
#pragma unroll
        for (int d = 0; d < DIM; ++d) {
          gi = fmaf(as_[j][d], wi[d], gi);
          gh = fmaf(hs_[j][d], wh[d], gh);
        }
        if (tid < 2 * DIM) {
          rz[j][tid] = gi + gh;
        } else {
          nn[j][0][tid - 2 * DIM] = gi;
          nn[j][1][tid - 2 * DIM] = gh;
        }
      }
    }
    __syncthreads();
    {
      int j = tid >> 6, d = tid & 63;
      int node = base + j;
      if (node < n_nodes) {
        float r = sigmoidf(rz[j][d]);
        float z = sigmoidf(rz[j][DIM + d]);
        float nv = tanhf(nn[j][0][d] + r * nn[j][1][d]);
        float ho = hs_[j][d];
        h[(size_t)node * DIM + d] = (1.0f - z) * nv + z * ho;
      }
    }
  }
}

extern "C" void kernel_launch(void* const* d_in, const int* in_sizes, int n_in,
                              void* d_out, int out_size, void* d_ws, size_t ws_size,
                              hipStream_t stream) {
  const float* feat = (const float*)d_in[0];
  const float* W    = (const float*)d_in[1];
  const float* b    = (const float*)d_in[2];
  const float* w_ih = (const float*)d_in[3];
  const float* w_hh = (const float*)d_in[4];
  const float* b_ih = (const float*)d_in[5];
  const float* b_hh = (const float*)d_in[6];
  const int* src = (const int*)d_in[7];
  const int* dst = (const int*)d_in[8];
  const int* et  = (const int*)d_in[9];

  const int n_nodes = in_sizes[0] / DIM;  // 50000
  const int n_edges = in_sizes[7];        // 800000

  float* h     = (float*)d_out;                    // [N, 64], doubles as h state
  float* h_all = (float*)d_ws;                     // [N, 256]
  float* abuf  = h_all + (size_t)n_nodes * TD;     // [N, 64]

  hipMemcpyAsync(h, feat, (size_t)n_nodes * DIM * sizeof(float),
                 hipMemcpyDeviceToDevice, stream);

  const int tgrid = 1024;
  const int egrid = (n_edges * 16 + 255) / 256;

  for (int s = 0; s < NSTEPS; ++s) {
    k_transform<<<tgrid, 256, 0, stream>>>(h, W, b, h_all, n_nodes);
    hipMemsetAsync(abuf, 0, (size_t)n_nodes * DIM * sizeof(float), stream);
    k_edge<<<egrid, 256, 0, stream>>>(h_all, src, dst, et, abuf, n_edges);
    k_gru<<<tgrid, 256, 0, stream>>>(abuf, h, w_ih, w_hh, b_ih, b_hh, n_nodes);
  }
}

// Round 2
// 972.341 us; speedup vs baseline: 4.2848x; 4.2848x over previous
//
#include <hip/hip_runtime.h>
#include <hip/hip_bf16.h>
#include <cstdint>

#define DIM 64
#define NT 4
#define TD 256   // NT*DIM
#define NSTEPS 5

__device__ __forceinline__ float sigmoidf(float x) { return 1.0f / (1.0f + expf(-x)); }

// ---------------- transform: h_all[n,t,e] = sum_d h[n,d]*W[t,e,d] + b[t,e] ----
__global__ __launch_bounds__(256, 2) void k_transform(
    const float* __restrict__ h, const float* __restrict__ W,
    const float* __restrict__ b, float* __restrict__ h_all, int n_nodes) {
  const int tid = threadIdx.x;
  float wreg[DIM];
#pragma unroll
  for (int d4 = 0; d4 < DIM / 4; ++d4) {
    float4 v = *(const float4*)(W + (size_t)tid * DIM + d4 * 4);
    wreg[d4 * 4 + 0] = v.x; wreg[d4 * 4 + 1] = v.y;
    wreg[d4 * 4 + 2] = v.z; wreg[d4 * 4 + 3] = v.w;
  }
  const float bias = b[tid];
  __shared__ float hs[4][DIM];

  for (int base = blockIdx.x * 4; base < n_nodes; base += gridDim.x * 4) {
    __syncthreads();
    {
      int idx = base * DIM + tid;
      ((float*)hs)[tid] = (idx < n_nodes * DIM) ? h[idx] : 0.0f;
    }
    __syncthreads();
#pragma unroll
    for (int j = 0; j < 4; ++j) {
      if (base + j >= n_nodes) break;
      float acc = bias;
#pragma unroll
      for (int d = 0; d < DIM; ++d) acc = fmaf(hs[j][d], wreg[d], acc);
      h_all[(size_t)(base + j) * TD + tid] = acc;
    }
  }
}

// ---------------- CSR build (once per launch) --------------------------------
__global__ __launch_bounds__(256) void k_count(const int* __restrict__ dst,
                                               int* __restrict__ counts, int n_edges) {
  int e = blockIdx.x * 256 + threadIdx.x;
  if (e < n_edges) atomicAdd(&counts[dst[e]], 1);
}

// per-block partial sums of counts
__global__ __launch_bounds__(256) void k_scan_partial(const int* __restrict__ counts,
                                                      int* __restrict__ partials, int n) {
  __shared__ int s[256];
  int gid = blockIdx.x * 256 + threadIdx.x;
  int v = (gid < n) ? counts[gid] : 0;
  s[threadIdx.x] = v;
  __syncthreads();
  for (int off = 128; off > 0; off >>= 1) {
    if (threadIdx.x < off) s[threadIdx.x] += s[threadIdx.x + off];
    __syncthreads();
  }
  if (threadIdx.x == 0) partials[blockIdx.x] = s[0];
}

// single-block exclusive scan of partials; also writes row_ptr[n_nodes]=total
__global__ __launch_bounds__(256) void k_scan_top(int* __restrict__ partials, int np,
                                                  int* __restrict__ row_ptr, int n_nodes) {
  __shared__ int s[256];
  int tid = threadIdx.x;
  int v = (tid < np) ? partials[tid] : 0;
  s[tid] = v;
  __syncthreads();
  for (int off = 1; off < 256; off <<= 1) {
    int t = (tid >= off) ? s[tid - off] : 0;
    __syncthreads();
    s[tid] += t;
    __syncthreads();
  }
  if (tid < np) partials[tid] = s[tid] - v;  // exclusive
  if (tid == 255) row_ptr[n_nodes] = s[255]; // total
}

// per-block scan of counts + add partial offset -> row_ptr (exclusive) & cursor
__global__ __launch_bounds__(256) void k_scan_final(const int* __restrict__ counts,
                                                    const int* __restrict__ partials,
                                                    int* __restrict__ row_ptr,
                                                    int* __restrict__ cursor, int n) {
  __shared__ int s[256];
  int gid = blockIdx.x * 256 + threadIdx.x;
  int tid = threadIdx.x;
  int v = (gid < n) ? counts[gid] : 0;
  s[tid] = v;
  __syncthreads();
  for (int off = 1; off < 256; off <<= 1) {
    int t = (tid >= off) ? s[tid - off] : 0;
    __syncthreads();
    s[tid] += t;
    __syncthreads();
  }
  if (gid < n) {
    int ex = partials[blockIdx.x] + s[tid] - v;
    row_ptr[gid] = ex;
    cursor[gid] = ex;
  }
}

__global__ __launch_bounds__(256) void k_scatter(const int* __restrict__ src,
                                                 const int* __restrict__ dst,
                                                 const int* __restrict__ et,
                                                 int* __restrict__ cursor,
                                                 int* __restrict__ csr, int n_edges) {
  int e = blockIdx.x * 256 + threadIdx.x;
  if (e >= n_edges) return;
  int pos = atomicAdd(&cursor[dst[e]], 1);
  csr[pos] = (src[e] << 2) | et[e];
}

// ---------------- gather-aggregate: a[n] = sum over incoming edges -----------
// 16 lanes per node, each lane owns one float4 of the 64-dim row.
__global__ __launch_bounds__(256) void k_agg(
    const float* __restrict__ h_all, const int* __restrict__ row_ptr,
    const int* __restrict__ csr, float* __restrict__ a, int n_nodes) {
  int gid = blockIdx.x * 256 + threadIdx.x;
  int node = gid >> 4;
  if (node >= n_nodes) return;
  int q = gid & 15;
  int beg = row_ptr[node];
  int end = row_ptr[node + 1];
  float4 acc = make_float4(0.f, 0.f, 0.f, 0.f);
  int i = beg;
  for (; i + 1 < end; i += 2) {
    int p0 = csr[i], p1 = csr[i + 1];
    const float4 v0 = *(const float4*)(h_all + (size_t)(p0 >> 2) * TD + (p0 & 3) * DIM + q * 4);
    const float4 v1 = *(const float4*)(h_all + (size_t)(p1 >> 2) * TD + (p1 & 3) * DIM + q * 4);
    acc.x += v0.x + v1.x; acc.y += v0.y + v1.y;
    acc.z += v0.z + v1.z; acc.w += v0.w + v1.w;
  }
  if (i < end) {
    int p0 = csr[i];
    const float4 v0 = *(const float4*)(h_all + (size_t)(p0 >> 2) * TD + (p0 & 3) * DIM + q * 4);
    acc.x += v0.x; acc.y += v0.y; acc.z += v0.z; acc.w += v0.w;
  }
  *(float4*)(a + (size_t)node * DIM + q * 4) = acc;
}

// ---------------- GRU --------------------------------------------------------
__global__ __launch_bounds__(256, 2) void k_gru(
    const float* __restrict__ a, float* __restrict__ h,
    const float* __restrict__ w_ih, const float* __restrict__ w_hh,
    const float* __restrict__ b_ih, const float* __restrict__ b_hh,
    int n_nodes) {
  const int tid = threadIdx.x;
  float wi[DIM], wh[DIM];
  float bi = 0.0f, bh = 0.0f;
  if (tid < 3 * DIM) {
#pragma unroll
    for (int d4 = 0; d4 < DIM / 4; ++d4) {
      float4 v = *(const float4*)(w_ih + (size_t)tid * DIM + d4 * 4);
      wi[d4 * 4 + 0] = v.x; wi[d4 * 4 + 1] = v.y;
      wi[d4 * 4 + 2] = v.z; wi[d4 * 4 + 3] = v.w;
      float4 u = *(const float4*)(w_hh + (size_t)tid * DIM + d4 * 4);
      wh[d4 * 4 + 0] = u.x; wh[d4 * 4 + 1] = u.y;
      wh[d4 * 4 + 2] = u.z; wh[d4 * 4 + 3] = u.w;
    }
    bi = b_ih[tid];
    bh = b_hh[tid];
  }

  __shared__ float as_[4][DIM];
  __shared__ float hs_[4][DIM];
  __shared__ float rz[4][2 * DIM];
  __shared__ float nn[4][2][DIM];

  for (int base = blockIdx.x * 4; base < n_nodes; base += gridDim.x * 4) {
    __syncthreads();
    {
      int idx = base * DIM + tid;
      bool ok = idx < n_nodes * DIM;
      ((float*)as_)[tid] = ok ? a[idx] : 0.0f;
      ((float*)hs_)[tid] = ok ? h[idx] : 0.0f;
    }
    __syncthreads();
    if (tid < 3 * DIM) {
#pragma unroll
      for (int j = 0; j < 4; ++j) {
        float gi = bi, gh = bh;
#pragma unroll
        for (int d = 0; d < DIM; ++d) {
          gi = fmaf(as_[j][d], wi[d], gi);
          gh = fmaf(hs_[j][d], wh[d], gh);
        }
        if (tid < 2 * DIM) {
          rz[j][tid] = gi + gh;
        } else {
          nn[j][0][tid - 2 * DIM] = gi;
          nn[j][1][tid - 2 * DIM] = gh;
        }
      }
    }
    __syncthreads();
    {
      int j = tid >> 6, d = tid & 63;
      int node = base + j;
      if (node < n_nodes) {
        float r = sigmoidf(rz[j][d]);
        float z = sigmoidf(rz[j][DIM + d]);
        float nv = tanhf(nn[j][0][d] + r * nn[j][1][d]);
        float ho = hs_[j][d];
        h[(size_t)node * DIM + d] = (1.0f - z) * nv + z * ho;
      }
    }
  }
}

extern "C" void kernel_launch(void* const* d_in, const int* in_sizes, int n_in,
                              void* d_out, int out_size, void* d_ws, size_t ws_size,
                              hipStream_t stream) {
  const float* feat = (const float*)d_in[0];
  const float* W    = (const float*)d_in[1];
  const float* b    = (const float*)d_in[2];
  const float* w_ih = (const float*)d_in[3];
  const float* w_hh = (const float*)d_in[4];
  const float* b_ih = (const float*)d_in[5];
  const float* b_hh = (const float*)d_in[6];
  const int* src = (const int*)d_in[7];
  const int* dst = (const int*)d_in[8];
  const int* et  = (const int*)d_in[9];

  const int n_nodes = in_sizes[0] / DIM;  // 50000
  const int n_edges = in_sizes[7];        // 800000

  float* h     = (float*)d_out;                        // [N, 64] state
  char* ws = (char*)d_ws;
  float* h_all = (float*)ws;                            ws += (size_t)n_nodes * TD * sizeof(float);
  float* abuf  = (float*)ws;                            ws += (size_t)n_nodes * DIM * sizeof(float);
  int* csr     = (int*)ws;                              ws += (size_t)n_edges * sizeof(int);
  int* row_ptr = (int*)ws;                              ws += (size_t)(n_nodes + 1) * sizeof(int);
  int* counts  = (int*)ws;                              ws += (size_t)n_nodes * sizeof(int);
  int* cursor  = (int*)ws;                              ws += (size_t)n_nodes * sizeof(int);
  int* partials= (int*)ws;                              ws += 256 * sizeof(int);

  hipMemcpyAsync(h, feat, (size_t)n_nodes * DIM * sizeof(float),
                 hipMemcpyDeviceToDevice, stream);

  // ---- build CSR by dst (same every call; deterministic work) ----
  const int nblk_nodes = (n_nodes + 255) / 256;   // 196
  const int nblk_edges = (n_edges + 255) / 256;
  hipMemsetAsync(counts, 0, (size_t)n_nodes * sizeof(int), stream);
  k_count<<<nblk_edges, 256, 0, stream>>>(dst, counts, n_edges);
  k_scan_partial<<<nblk_nodes, 256, 0, stream>>>(counts, partials, n_nodes);
  k_scan_top<<<1, 256, 0, stream>>>(partials, nblk_nodes, row_ptr, n_nodes);
  k_scan_final<<<nblk_nodes, 256, 0, stream>>>(counts, partials, row_ptr, cursor, n_nodes);
  k_scatter<<<nblk_edges, 256, 0, stream>>>(src, dst, et, cursor, csr, n_edges);

  const int tgrid = 1024;
  const int agrid = (n_nodes * 16 + 255) / 256;

  for (int s = 0; s < NSTEPS; ++s) {
    k_transform<<<tgrid, 256, 0, stream>>>(h, W, b, h_all, n_nodes);
    k_agg<<<agrid, 256, 0, stream>>>(h_all, row_ptr, csr, abuf, n_nodes);
    k_gru<<<tgrid, 256, 0, stream>>>(abuf, h, w_ih, w_hh, b_ih, b_hh, n_nodes);
  }
}